// Round 1
// baseline (398.343 us; speedup 1.0000x reference)
//
#include <hip/hip_runtime.h>

typedef unsigned short u16;
typedef __attribute__((ext_vector_type(8))) short bf16x8;
typedef __attribute__((ext_vector_type(4))) float f32x4;

#define MFMA16(a, b, c) __builtin_amdgcn_mfma_f32_16x16x32_bf16(a, b, c, 0, 0, 0)

__device__ __forceinline__ u16 f2bf(float f) {
  union { float f; unsigned u; } v; v.f = f;
  unsigned r = v.u + 0x7fffu + ((v.u >> 16) & 1u);
  return (u16)(r >> 16);
}

// ---------------- pack: weights -> bf16 fragment layout, bias table -> bias_full ----
// wpack  [36 ntiles][6 ks][64 lane][8]  from wqkv_w[192][576]
// wppack [12 ntiles][6 ks][64 lane][8]  from wp_w[192][192]
// bias_full[6][64][64]                  from bias_table[225][6]
__global__ void pack_kernel(const float* __restrict__ wqkv_w,
                            const float* __restrict__ wp_w,
                            const float* __restrict__ bias_table,
                            u16* __restrict__ wpack, u16* __restrict__ wppack,
                            float* __restrict__ bias_full) {
  int i = blockIdx.x * 256 + threadIdx.x;
  if (i < 110592) {
    int j = i & 7, l = (i >> 3) & 63;
    int rest = i >> 9;
    int ks = rest % 6, nt = rest / 6;
    int k = ks * 32 + (l >> 4) * 8 + j;
    int n = nt * 16 + (l & 15);
    wpack[i] = f2bf(wqkv_w[k * 576 + n]);
  } else if (i < 147456) {
    int i2 = i - 110592;
    int j = i2 & 7, l = (i2 >> 3) & 63;
    int rest = i2 >> 9;
    int ks = rest % 6, nt = rest / 6;
    int k = ks * 32 + (l >> 4) * 8 + j;
    int n = nt * 16 + (l & 15);
    wppack[i2] = f2bf(wp_w[k * 192 + n]);
  } else if (i < 172032) {
    int i2 = i - 147456;
    int kk = i2 & 63, q = (i2 >> 6) & 63, h = i2 >> 12;
    int r1 = q >> 3, c1 = q & 7, r2 = kk >> 3, c2 = kk & 7;
    int idx = (r1 - r2 + 7) * 15 + (c1 - c2 + 7);
    bias_full[i2] = bias_table[idx * 6 + h];
  }
}

// ---------------- fused window qkv + attention ----------------
// 1 block = 1 window (64 tokens); 6 waves = 6 heads.
// LDS (u16 units):
//   xs  [64][200]  at 0       (phase 1)          12800 u16
//   ps  [64][72]   at wv*4608 (phase 2, aliases xs) 6*4608 = 27648 u16
//   qh  [64][40]   at 27648 + wv*7424
//   kh  [64][40]   qh + 2560
//   vth [32][72]   kh + 2560
// total 72192 u16 = 144384 B
__global__ __launch_bounds__(384, 1) void win_attn(
    const float* __restrict__ x, const u16* __restrict__ wpack,
    const float* __restrict__ wqkv_b, const float* __restrict__ bias_full,
    u16* __restrict__ y) {
  __shared__ u16 lds[72192];
  const int tid = threadIdx.x;
  const int lane = tid & 63;
  const int wv = tid >> 6;            // head
  const int g = lane >> 4, li = lane & 15;
  const int blk = blockIdx.x;
  const int bb = blk / 576, rem = blk % 576, wy = rem / 24, wx = rem % 24;

  u16* xs = lds;
  u16* ps = lds + wv * 4608;
  u16* qh = lds + 27648 + wv * 7424;
  u16* kh = qh + 2560;
  u16* vth = kh + 2560;

  // ---- stage x window into LDS as bf16 ----
  {
    const int tk = tid / 6, part = tid % 6;      // 64 tokens x 6 parts (32 cols each)
    const int rr = tk >> 3, cc = tk & 7;
    const float* xrow = x + (size_t)(bb * 36864 + (wy * 8 + rr) * 192 + wx * 8 + cc) * 192 + part * 32;
    u16* dst = xs + tk * 200 + part * 32;
#pragma unroll
    for (int it = 0; it < 8; ++it) {
      float4 f = ((const float4*)xrow)[it];
      ushort4 o;
      o.x = f2bf(f.x); o.y = f2bf(f.y); o.z = f2bf(f.z); o.w = f2bf(f.w);
      *(ushort4*)(dst + it * 4) = o;
    }
  }
  __syncthreads();

  // ---- qkv GEMM for this head: [64,192] @ [192, 3*32] ----
  f32x4 zero4 = {0.f, 0.f, 0.f, 0.f};
  f32x4 aq[4][2], ak[4][2], av[4][2];
#pragma unroll
  for (int mt = 0; mt < 4; ++mt)
#pragma unroll
    for (int i = 0; i < 2; ++i) { aq[mt][i] = zero4; ak[mt][i] = zero4; av[mt][i] = zero4; }

#pragma unroll
  for (int ks = 0; ks < 6; ++ks) {
    bf16x8 af[4];
#pragma unroll
    for (int mt = 0; mt < 4; ++mt)
      af[mt] = *(const bf16x8*)(xs + (mt * 16 + li) * 200 + ks * 32 + g * 8);
    const u16* wbase = wpack + ks * 512 + lane * 8;   // tile stride = 6*512 = 3072
    bf16x8 bq[2], bk[2], bv[2];
#pragma unroll
    for (int i = 0; i < 2; ++i) {
      bq[i] = *(const bf16x8*)(wbase + (2 * wv + i) * 3072);
      bk[i] = *(const bf16x8*)(wbase + (12 + 2 * wv + i) * 3072);
      bv[i] = *(const bf16x8*)(wbase + (24 + 2 * wv + i) * 3072);
    }
#pragma unroll
    for (int mt = 0; mt < 4; ++mt)
#pragma unroll
      for (int i = 0; i < 2; ++i) {
        aq[mt][i] = MFMA16(af[mt], bq[i], aq[mt][i]);
        ak[mt][i] = MFMA16(af[mt], bk[i], ak[mt][i]);
        av[mt][i] = MFMA16(af[mt], bv[i], av[mt][i]);
      }
  }

  // bias + q-scale, store q/k/v to LDS in fragment-friendly layouts
  const float scale = 0.17677669529663687f;   // 1/sqrt(32)
#pragma unroll
  for (int i = 0; i < 2; ++i) {
    float bqs = wqkv_b[wv * 32 + i * 16 + li];
    float bks = wqkv_b[192 + wv * 32 + i * 16 + li];
    float bvs = wqkv_b[384 + wv * 32 + i * 16 + li];
#pragma unroll
    for (int mt = 0; mt < 4; ++mt)
#pragma unroll
      for (int r = 0; r < 4; ++r) {
        int tok = mt * 16 + g * 4 + r;
        qh[tok * 40 + i * 16 + li] = f2bf((aq[mt][i][r] + bqs) * scale);
        kh[tok * 40 + i * 16 + li] = f2bf(ak[mt][i][r] + bks);
        vth[(i * 16 + li) * 72 + tok] = f2bf(av[mt][i][r] + bvs);
      }
  }
  __syncthreads();   // also fences xs reads before ps (alias) writes below

  // ---- S = Q K^T (+bias) ----
  bf16x8 qa[4], kb[4];
#pragma unroll
  for (int mt = 0; mt < 4; ++mt) qa[mt] = *(const bf16x8*)(qh + (mt * 16 + li) * 40 + g * 8);
#pragma unroll
  for (int nt = 0; nt < 4; ++nt) kb[nt] = *(const bf16x8*)(kh + (nt * 16 + li) * 40 + g * 8);
  f32x4 sc[4][4];
#pragma unroll
  for (int mt = 0; mt < 4; ++mt)
#pragma unroll
    for (int nt = 0; nt < 4; ++nt) sc[mt][nt] = MFMA16(qa[mt], kb[nt], zero4);

  // ---- softmax over keys (rows = q tokens), write P to LDS bf16 ----
  const float* bf_h = bias_full + wv * 4096;
#pragma unroll
  for (int mt = 0; mt < 4; ++mt)
#pragma unroll
    for (int r = 0; r < 4; ++r) {
      int q = mt * 16 + g * 4 + r;
      float v0 = sc[mt][0][r] + bf_h[q * 64 + li];
      float v1 = sc[mt][1][r] + bf_h[q * 64 + 16 + li];
      float v2 = sc[mt][2][r] + bf_h[q * 64 + 32 + li];
      float v3 = sc[mt][3][r] + bf_h[q * 64 + 48 + li];
      float m = fmaxf(fmaxf(v0, v1), fmaxf(v2, v3));
#pragma unroll
      for (int msk = 1; msk < 16; msk <<= 1) m = fmaxf(m, __shfl_xor(m, msk));
      float e0 = __expf(v0 - m), e1 = __expf(v1 - m), e2 = __expf(v2 - m), e3 = __expf(v3 - m);
      float s = e0 + e1 + e2 + e3;
#pragma unroll
      for (int msk = 1; msk < 16; msk <<= 1) s += __shfl_xor(s, msk);
      float inv = 1.0f / s;
      ps[q * 72 + li]      = f2bf(e0 * inv);
      ps[q * 72 + 16 + li] = f2bf(e1 * inv);
      ps[q * 72 + 32 + li] = f2bf(e2 * inv);
      ps[q * 72 + 48 + li] = f2bf(e3 * inv);
    }

  // ---- Y = P V ----
  f32x4 ya[4][2];
#pragma unroll
  for (int mt = 0; mt < 4; ++mt) { ya[mt][0] = zero4; ya[mt][1] = zero4; }
#pragma unroll
  for (int ks2 = 0; ks2 < 2; ++ks2) {
    bf16x8 pa[4], vb[2];
#pragma unroll
    for (int mt = 0; mt < 4; ++mt)
      pa[mt] = *(const bf16x8*)(ps + (mt * 16 + li) * 72 + ks2 * 32 + g * 8);
#pragma unroll
    for (int i = 0; i < 2; ++i)
      vb[i] = *(const bf16x8*)(vth + (i * 16 + li) * 72 + ks2 * 32 + g * 8);
#pragma unroll
    for (int mt = 0; mt < 4; ++mt)
#pragma unroll
      for (int i = 0; i < 2; ++i) ya[mt][i] = MFMA16(pa[mt], vb[i], ya[mt][i]);
  }

  // ---- store y (bf16, linear [b, H*W, c]) ----
#pragma unroll
  for (int mt = 0; mt < 4; ++mt)
#pragma unroll
    for (int i = 0; i < 2; ++i)
#pragma unroll
      for (int r = 0; r < 4; ++r) {
        int tok = mt * 16 + g * 4 + r;
        int pix = (wy * 8 + (tok >> 3)) * 192 + wx * 8 + (tok & 7);
        y[(size_t)(bb * 36864 + pix) * 192 + wv * 32 + i * 16 + li] = f2bf(ya[mt][i][r]);
      }
}

// ---------------- projection GEMM: out = y @ wp + b ----------------
__global__ __launch_bounds__(256) void proj_kernel(
    const u16* __restrict__ y, const u16* __restrict__ wppack,
    const float* __restrict__ wp_b, float* __restrict__ out) {
  __shared__ u16 ysh[128 * 200];
  const int tid = threadIdx.x;
  const int lane = tid & 63, wv = tid >> 6;
  const int g = lane >> 4, li = lane & 15;
  const size_t row0 = (size_t)blockIdx.x * 128;
#pragma unroll
  for (int it = 0; it < 12; ++it) {
    int idx = it * 256 + tid;                 // 3072 x 16B chunks
    int rr = idx / 24, cc = (idx % 24) * 8;
    *(uint4*)(ysh + rr * 200 + cc) = *(const uint4*)(y + (row0 + rr) * 192 + cc);
  }
  __syncthreads();
  f32x4 zero4 = {0.f, 0.f, 0.f, 0.f};
  f32x4 acc[2][12];
#pragma unroll
  for (int mt = 0; mt < 2; ++mt)
#pragma unroll
    for (int nt = 0; nt < 12; ++nt) acc[mt][nt] = zero4;
#pragma unroll
  for (int ks = 0; ks < 6; ++ks) {
    bf16x8 af[2];
#pragma unroll
    for (int mt = 0; mt < 2; ++mt)
      af[mt] = *(const bf16x8*)(ysh + (wv * 32 + mt * 16 + li) * 200 + ks * 32 + g * 8);
#pragma unroll
    for (int nt = 0; nt < 12; ++nt) {
      bf16x8 bf = *(const bf16x8*)(wppack + nt * 3072 + ks * 512 + lane * 8);
      acc[0][nt] = MFMA16(af[0], bf, acc[0][nt]);
      acc[1][nt] = MFMA16(af[1], bf, acc[1][nt]);
    }
  }
#pragma unroll
  for (int nt = 0; nt < 12; ++nt) {
    float bb = wp_b[nt * 16 + li];
#pragma unroll
    for (int mt = 0; mt < 2; ++mt)
#pragma unroll
      for (int r = 0; r < 4; ++r)
        out[(row0 + wv * 32 + mt * 16 + g * 4 + r) * 192 + nt * 16 + li] = acc[mt][nt][r] + bb;
  }
}

extern "C" void kernel_launch(void* const* d_in, const int* in_sizes, int n_in,
                              void* d_out, int out_size, void* d_ws, size_t ws_size,
                              hipStream_t stream) {
  (void)in_sizes; (void)n_in; (void)out_size; (void)ws_size;
  const float* x          = (const float*)d_in[0];
  const float* wqkv_w     = (const float*)d_in[1];
  const float* wqkv_b     = (const float*)d_in[2];
  const float* wp_w       = (const float*)d_in[3];
  const float* wp_b       = (const float*)d_in[4];
  const float* bias_table = (const float*)d_in[5];
  float* out = (float*)d_out;
  char* ws = (char*)d_ws;
  u16* wpack      = (u16*)(ws);               // 221184 B
  u16* wppack     = (u16*)(ws + 221184);      //  73728 B
  float* bias_full = (float*)(ws + 294912);   //  98304 B
  u16* y          = (u16*)(ws + 393216);      // 113246208 B

  pack_kernel<<<672, 256, 0, stream>>>(wqkv_w, wp_w, bias_table, wpack, wppack, bias_full);
  win_attn<<<4608, 384, 0, stream>>>(x, wpack, wqkv_b, bias_full, y);
  proj_kernel<<<2304, 256, 0, stream>>>(y, wppack, wp_b, out);
}